// Round 9
// baseline (587.508 us; speedup 1.0000x reference)
//
#include <hip/hip_runtime.h>
#include <cstdint>
#include <cstddef>

#define NN   10000
#define NE   160000
#define NB   16
#define FIN  32
#define HC   16
#define NH   4
#define HD   4
#define OBSD 100
#define NOUT 30
#define HIDD 128
#define PO   15
#define BCAP 64
#define NBUCKET 64
#define NBLK 512
#define NTHR 256
#define GSIZE (NBLK * NTHR)     // 131072
#define NWAVE (GSIZE / 64)      // 2048

typedef float floatx2 __attribute__((ext_vector_type(2)));

struct GParams {
    const int* src; const int* dst;
    int* bars; int* cnt; int* bucket;
    const float* x; const float* obs;
    const float* W0l; const float* W0r; const float* b0l; const float* b0r;
    const float* Wl; const float* Wr; const float* bl; const float* br;
    const float* att; const float* bias;
    const float* Wp; const float* bp;
    const float* W1; const float* b1;
    const float* W2; const float* b2;
    const float* W3; const float* b3;
    uint32_t* xlA; float* xrA; uint32_t* xlB; float* xrB;
    float* pool_part; float* out;
};

__device__ inline uint32_t pack_fp8x4(float a, float b, float c, float d) {
    int p = __builtin_amdgcn_cvt_pk_fp8_f32(a, b, 0, false);
    p = __builtin_amdgcn_cvt_pk_fp8_f32(c, d, p, true);
    return (uint32_t)p;
}

__device__ inline float4 shfl_xor4(float4 v, int m) {
    float4 r;
    r.x = __shfl_xor(v.x, m, 64);
    r.y = __shfl_xor(v.y, m, 64);
    r.z = __shfl_xor(v.z, m, 64);
    r.w = __shfl_xor(v.w, m, 64);
    return r;
}

// software grid barrier: monotone counter per phase (zeroed by host memset).
// all NBLK blocks are co-resident by construction (launch_bounds(256,2) ->
// >=2 blocks/CU guaranteed; 512 blocks on 256 CUs).
__device__ inline void gbar(int* bars, int idx) {
    __syncthreads();
    if (threadIdx.x == 0) {
        __threadfence();                       // device-scope release
        atomicAdd(&bars[idx], 1);              // device-scope arrival
        while (__hip_atomic_load(&bars[idx], __ATOMIC_ACQUIRE,
                                 __HIP_MEMORY_SCOPE_AGENT) < NBLK) {
            __builtin_amdgcn_s_sleep(8);
        }
    }
    __syncthreads();
}

__global__ __launch_bounds__(NTHR, 2) void k_mega(GParams p) {
    __shared__ float smem[1600];
    const int tid  = threadIdx.x;
    const int bid  = blockIdx.x;
    const int gtid = bid * NTHR + tid;
    const int lane = tid & 63;
    const int h    = lane & 3;
    const int wv   = gtid >> 6;

    // ---------------- phase 1: bucket scatter + xform0 ----------------
    for (int e = gtid; e < NE; e += GSIZE) {
        int d = p.dst[e];
        int pp = atomicAdd(&p.cnt[d], 1);
        if (pp < BCAP) p.bucket[(size_t)d * BCAP + pp] = p.src[e];
    }
    {
        float* sWl = smem;               // 512
        float* sWr = smem + 512;         // 512
        float* sbl = smem + 1024;        // 16
        float* sbr = smem + 1040;        // 16
        for (int i = tid; i < FIN * HC; i += NTHR) { sWl[i] = p.W0l[i]; sWr[i] = p.W0r[i]; }
        if (tid < HC) { sbl[tid] = p.b0l[tid]; sbr[tid] = p.b0r[tid]; }
        __syncthreads();
        for (int item = gtid; item < NN * NB; item += GSIZE) {
            int b = item / NN, n = item - b * NN;
            const float* xp = p.x + ((size_t)b * NN + n) * FIN;
            float row[FIN];
#pragma unroll
            for (int f = 0; f < FIN; f++) row[f] = xp[f];
            float al[HC], ar[HC];
#pragma unroll
            for (int c = 0; c < HC; c++) { al[c] = sbl[c]; ar[c] = sbr[c]; }
#pragma unroll
            for (int f = 0; f < FIN; f++) {
                float v = row[f];
#pragma unroll
                for (int c = 0; c < HC; c++) {
                    al[c] = fmaf(v, sWl[f * HC + c], al[c]);
                    ar[c] = fmaf(v, sWr[f * HC + c], ar[c]);
                }
            }
            uint32_t* xlo = p.xlA + ((size_t)n * NB + b) * 4;
            float*    xro = p.xrA + ((size_t)n * NB + b) * HC;
#pragma unroll
            for (int hh = 0; hh < 4; hh++)
                xlo[hh] = pack_fp8x4(al[hh * 4 + 0], al[hh * 4 + 1], al[hh * 4 + 2], al[hh * 4 + 3]);
#pragma unroll
            for (int c = 0; c < HC; c++) xro[c] = ar[c];
        }
    }
    gbar(p.bars, 0);

    // ---------------- phases 2..5: 4 edge layers ----------------
    float* sWl2 = smem;          // 256
    float* sWr2 = smem + 256;    // 256
    float* sbl2 = smem + 512;    // 16
    float* sbr2 = smem + 528;    // 16
    float* sRed = smem + 544;    // 1024

    for (int layer = 0; layer < 4; layer++) {
        const uint32_t* xl   = (layer & 1) ? p.xlB : p.xlA;
        const float*    xr   = (layer & 1) ? p.xrB : p.xrA;
        uint32_t*       xl_o = (layer & 1) ? p.xlA : p.xlB;
        float*          xr_o = (layer & 1) ? p.xrA : p.xrB;
        if (layer < 3) {
            for (int i = tid; i < HC * HC; i += NTHR) {
                sWl2[i] = p.Wl[layer * 256 + i];
                sWr2[i] = p.Wr[layer * 256 + i];
            }
            if (tid < HC) { sbl2[tid] = p.bl[layer * 16 + tid]; sbr2[tid] = p.br[layer * 16 + tid]; }
            __syncthreads();
        }
        const float4 a4    = *(const float4*)(p.att  + layer * 16 + h * HD);
        const float4 bias4 = *(const float4*)(p.bias + layer * 16 + h * HD);
        float psum0 = 0.f, psum1 = 0.f, psum2 = 0.f, psum3 = 0.f;

        for (int n = wv; n < NN; n += NWAVE) {
            const float4 xr4 = *(const float4*)(xr + (size_t)n * (NB * HC) + lane * 4);
            int cnt = __builtin_amdgcn_readfirstlane(p.cnt[n]);
            cnt = cnt < BCAP ? cnt : BCAP;
            float4 acc = make_float4(0.f, 0.f, 0.f, 0.f);
            float ssum = 0.f;

#define EDGE_BODY(RAW, M)                                                     \
    {                                                                         \
        floatx2 f0 = __builtin_amdgcn_cvt_pk_f32_fp8((int)(RAW), false);      \
        floatx2 f1 = __builtin_amdgcn_cvt_pk_f32_fp8((int)(RAW), true);       \
        float z0 = f0.x + xr4.x; z0 = fmaxf(z0, 0.2f * z0);                   \
        float z1 = f0.y + xr4.y; z1 = fmaxf(z1, 0.2f * z1);                   \
        float z2 = f1.x + xr4.z; z2 = fmaxf(z2, 0.2f * z2);                   \
        float z3 = f1.y + xr4.w; z3 = fmaxf(z3, 0.2f * z3);                   \
        float e = fmaf(z3, a4.w, fmaf(z2, a4.z, fmaf(z1, a4.y, z0 * a4.x)));  \
        float ex = (M) * __expf(e);                                           \
        ssum += ex;                                                           \
        acc.x = fmaf(ex, f0.x, acc.x);                                        \
        acc.y = fmaf(ex, f0.y, acc.y);                                        \
        acc.z = fmaf(ex, f1.x, acc.z);                                        \
        acc.w = fmaf(ex, f1.y, acc.w);                                        \
    }
#define GATHER(S) xl[(size_t)(S) * 64 + lane]

            { const uint32_t r = GATHER(n); EDGE_BODY(r, 1.0f); }   // self loop
            if (cnt > 0) {
                const int* brow = p.bucket + (size_t)n * BCAP;
                int li = lane < cnt ? lane : cnt - 1;
                int vidx = brow[li];
                for (int i = 0; i < cnt; i += 16) {
                    uint32_t r[16];
#pragma unroll
                    for (int u = 0; u < 16; u++) {
                        int e = i + u;
                        int ec = e < cnt ? e : cnt - 1;
                        int s = __builtin_amdgcn_readlane(vidx, ec);
                        r[u] = GATHER(s);
                    }
#pragma unroll
                    for (int u = 0; u < 16; u++) {
                        float m = (i + u < cnt) ? 1.0f : 0.0f;
                        EDGE_BODY(r[u], m);
                    }
                }
            }
#undef GATHER
#undef EDGE_BODY

            float inv = 1.0f / (ssum + 1e-16f);
            float4 o;
            o.x = fmaf(acc.x, inv, bias4.x);
            o.y = fmaf(acc.y, inv, bias4.y);
            o.z = fmaf(acc.z, inv, bias4.z);
            o.w = fmaf(acc.w, inv, bias4.w);

            if (layer < 3) {
                float accl[4], accr[4];
#pragma unroll
                for (int cj = 0; cj < 4; cj++) {
                    accl[cj] = sbl2[h * 4 + cj];
                    accr[cj] = sbr2[h * 4 + cj];
                }
#pragma unroll
                for (int m = 0; m < 4; m++) {
                    float4 vals = (m == 0) ? o : shfl_xor4(o, m);
                    int fbase = ((h ^ m) << 2);
                    float vv[4] = {vals.x, vals.y, vals.z, vals.w};
#pragma unroll
                    for (int j = 0; j < 4; j++) {
                        const float4 wl = *(const float4*)&sWl2[(fbase + j) * HC + (h << 2)];
                        const float4 wr = *(const float4*)&sWr2[(fbase + j) * HC + (h << 2)];
                        float v = vv[j];
                        accl[0] = fmaf(v, wl.x, accl[0]);
                        accl[1] = fmaf(v, wl.y, accl[1]);
                        accl[2] = fmaf(v, wl.z, accl[2]);
                        accl[3] = fmaf(v, wl.w, accl[3]);
                        accr[0] = fmaf(v, wr.x, accr[0]);
                        accr[1] = fmaf(v, wr.y, accr[1]);
                        accr[2] = fmaf(v, wr.z, accr[2]);
                        accr[3] = fmaf(v, wr.w, accr[3]);
                    }
                }
                xl_o[(size_t)n * 64 + lane] = pack_fp8x4(accl[0], accl[1], accl[2], accl[3]);
                *(float4*)(xr_o + (size_t)n * (NB * HC) + lane * 4) =
                    make_float4(accr[0], accr[1], accr[2], accr[3]);
            } else {
                psum0 += o.x; psum1 += o.y; psum2 += o.z; psum3 += o.w;
            }
        }

        if (layer == 3) {
            *(float4*)&sRed[tid * 4] = make_float4(psum0, psum1, psum2, psum3);
            __syncthreads();
            if (tid < 64) {
                float4 s0 = *(const float4*)&sRed[tid * 4];
                float4 s1 = *(const float4*)&sRed[(64 + tid) * 4];
                float4 s2 = *(const float4*)&sRed[(128 + tid) * 4];
                float4 s3 = *(const float4*)&sRed[(192 + tid) * 4];
                float* dp = p.pool_part + (bid & (NBUCKET - 1)) * 256 + tid * 4;
                atomicAdd(dp + 0, s0.x + s1.x + s2.x + s3.x);
                atomicAdd(dp + 1, s0.y + s1.y + s2.y + s3.y);
                atomicAdd(dp + 2, s0.z + s1.z + s2.z + s3.z);
                atomicAdd(dp + 3, s0.w + s1.w + s2.w + s3.w);
            }
        }
        gbar(p.bars, 1 + layer);
    }

    // ---------------- phase 6: head (blocks 0..15) ----------------
    if (bid < NB) {
        const int b = bid;
        const int t = tid;
        float* sPool = smem;         // 16
        float* sIn   = smem + 16;    // 115
        float* s1    = smem + 144;   // 128
        float* s2    = smem + 272;   // 128
        __syncthreads();
        if (t < HC) {
            float ps = 0.f;
            for (int q = 0; q < NBUCKET; q++) ps += p.pool_part[q * 256 + b * HC + t];
            sPool[t] = ps * (1.0f / NN);
        }
        for (int k = t; k < OBSD; k += NTHR) sIn[PO + k] = p.obs[b * OBSD + k];
        __syncthreads();
        if (t < PO) {
            float acc = p.bp[t];
#pragma unroll
            for (int c = 0; c < HC; c++) acc = fmaf(sPool[c], p.Wp[c * PO + t], acc);
            sIn[t] = acc;
        }
        __syncthreads();
        if (t < HIDD) {
            float acc = p.b1[t];
            for (int k = 0; k < PO + OBSD; k++) acc = fmaf(sIn[k], p.W1[k * HIDD + t], acc);
            s1[t] = tanhf(acc);
        }
        __syncthreads();
        if (t < HIDD) {
            float acc = p.b2[t];
            for (int k = 0; k < HIDD; k++) acc = fmaf(s1[k], p.W2[k * HIDD + t], acc);
            s2[t] = tanhf(acc);
        }
        __syncthreads();
        if (t < NOUT) {
            float acc = p.b3[t];
            for (int k = 0; k < HIDD; k++) acc = fmaf(s2[k], p.W3[k * NOUT + t], acc);
            p.out[b * NOUT + t] = acc;
        }
    }
}

extern "C" void kernel_launch(void* const* d_in, const int* in_sizes, int n_in,
                              void* d_out, int out_size, void* d_ws, size_t ws_size,
                              hipStream_t stream) {
    size_t off = 0;
    auto take = [&](size_t bytes) -> void* {
        void* ptr = (char*)d_ws + off;
        off += (bytes + 255) & ~(size_t)255;
        return ptr;
    };
    // bars + cnt + pool_part contiguous -> one zeroing memset
    int*      bars      = (int*)take(16 * sizeof(int));
    int*      cnt       = (int*)take(NN * sizeof(int));
    float*    pool_part = (float*)take(NBUCKET * 256 * sizeof(float));
    int*      bucket    = (int*)take((size_t)NN * BCAP * sizeof(int));
    uint32_t* xlA       = (uint32_t*)take((size_t)NN * 64 * sizeof(uint32_t));
    float*    xrA       = (float*)take((size_t)NN * NB * HC * sizeof(float));
    uint32_t* xlB       = (uint32_t*)take((size_t)NN * 64 * sizeof(uint32_t));
    float*    xrB       = (float*)take((size_t)NN * NB * HC * sizeof(float));

    size_t zspan = (size_t)((char*)(pool_part + NBUCKET * 256) - (char*)bars);
    hipMemsetAsync(bars, 0, zspan, stream);

    GParams p;
    p.src = (const int*)d_in[2];
    p.dst = (const int*)d_in[3];
    p.bars = bars; p.cnt = cnt; p.bucket = bucket;
    p.x   = (const float*)d_in[0];
    p.obs = (const float*)d_in[1];
    p.W0l = (const float*)d_in[4];
    p.W0r = (const float*)d_in[5];
    p.b0l = (const float*)d_in[6];
    p.b0r = (const float*)d_in[7];
    p.Wl  = (const float*)d_in[8];
    p.Wr  = (const float*)d_in[9];
    p.bl  = (const float*)d_in[10];
    p.br  = (const float*)d_in[11];
    p.att = (const float*)d_in[12];
    p.bias= (const float*)d_in[13];
    p.Wp  = (const float*)d_in[14];
    p.bp  = (const float*)d_in[15];
    p.W1  = (const float*)d_in[16];
    p.b1  = (const float*)d_in[17];
    p.W2  = (const float*)d_in[18];
    p.b2  = (const float*)d_in[19];
    p.W3  = (const float*)d_in[20];
    p.b3  = (const float*)d_in[21];
    p.xlA = xlA; p.xrA = xrA; p.xlB = xlB; p.xrB = xrB;
    p.pool_part = pool_part;
    p.out = (float*)d_out;

    k_mega<<<NBLK, NTHR, 0, stream>>>(p);
}